// Round 6
// baseline (989.856 us; speedup 1.0000x reference)
//
#include <hip/hip_runtime.h>
#include <math.h>

#define N_NODES 50000
#define N_EDGES 800000
#define IN_DIM  16
#define HID     64
#define NH      4
#define NGRAPH  128
#define OUT_DIM 32
#define NUM_LAYERS 8
#define NEG_SLOPE 0.2f

#define SCAN_BLOCKS ((N_NODES + 255) / 256)   // 196

typedef unsigned short u16;
typedef _Float16 h2   __attribute__((ext_vector_type(2)));
typedef _Float16 f16x8 __attribute__((ext_vector_type(8)));
typedef __attribute__((ext_vector_type(4))) float f32x4;

static __device__ __forceinline__ u16 f2h(float f) {
    _Float16 h = (_Float16)f; u16 r; __builtin_memcpy(&r, &h, 2); return r;
}
static __device__ __forceinline__ float h2f_lo(unsigned w) {
    _Float16 h; u16 u = (u16)w; __builtin_memcpy(&h, &u, 2); return (float)h;
}
static __device__ __forceinline__ h2 shfl_h2(h2 v, int mask) {
    int i; __builtin_memcpy(&i, &v, 4); i = __shfl_xor(i, mask);
    h2 r; __builtin_memcpy(&r, &i, 4); return r;
}
static __device__ __forceinline__ h2 bcast_h2(float f) {
    _Float16 h = (_Float16)f; h2 r; r[0] = h; r[1] = h; return r;
}

// DPP lane-xor within quads (VALU-only cross-lane reduce)
#define DPP_XOR1(x) __uint_as_float((unsigned)__builtin_amdgcn_update_dpp(0, (int)__float_as_uint(x), 0xB1, 0xF, 0xF, true))
#define DPP_XOR2(x) __uint_as_float((unsigned)__builtin_amdgcn_update_dpp(0, (int)__float_as_uint(x), 0x4E, 0xF, 0xF, true))

// ---------------- setup kernels ----------------

// Pack Wcat=[W_src|W_dst] (fp32 [128][512]) into MFMA-fragment-ordered f16:
// Wpack[((nt*4+kt)*64 + l)*8 + i] = Wcat[kt*32 + (l>>4)*8 + i][nt*16 + (l&15)]
// Also bcat[512] f32 and an_h[256] = f16(attn * log2e).
__global__ void k_build_wpack(const float* __restrict__ Wsrc, const float* __restrict__ bsrc,
                              const float* __restrict__ Wdst, const float* __restrict__ bdst,
                              const float* __restrict__ attn,
                              u16* __restrict__ Wpack, float* __restrict__ bcat,
                              u16* __restrict__ an_h) {
    int tid = blockIdx.x * 256 + threadIdx.x;   // 0..65535
    int i = tid & 7;
    int l = (tid >> 3) & 63;
    int rest = tid >> 9;          // 0..127
    int kt = rest & 3;
    int nt = rest >> 2;           // 0..31
    int k = kt * 32 + (l >> 4) * 8 + i;      // 0..127
    int col = nt * 16 + (l & 15);            // 0..511
    float v = (col < 256) ? Wsrc[k * 256 + col] : Wdst[k * 256 + (col - 256)];
    Wpack[tid] = f2h(v);
    if (tid < 512) bcat[tid] = (tid < 256) ? bsrc[tid] : bdst[tid - 256];
    if (tid < 256) an_h[tid] = f2h(attn[tid] * 1.44269504f);   // fold log2(e)
}

__global__ void k_hist(const int* __restrict__ dst, int* __restrict__ deg) {
    int e = blockIdx.x * 256 + threadIdx.x;
    if (e < N_EDGES) atomicAdd(&deg[dst[e]], 1);
}

__global__ void k_blocksum(const int* __restrict__ deg, int* __restrict__ bsum) {
    __shared__ int sm[256];
    int i = blockIdx.x * 256 + threadIdx.x;
    sm[threadIdx.x] = (i < N_NODES) ? deg[i] : 0;
    __syncthreads();
    for (int s = 128; s > 0; s >>= 1) {
        if (threadIdx.x < s) sm[threadIdx.x] += sm[threadIdx.x + s];
        __syncthreads();
    }
    if (threadIdx.x == 0) bsum[blockIdx.x] = sm[0];
}

__global__ void k_scanbsum(int* __restrict__ bsum) {
    if (threadIdx.x == 0 && blockIdx.x == 0) {
        int acc = 0;
        for (int b = 0; b < SCAN_BLOCKS; b++) { int t = bsum[b]; bsum[b] = acc; acc += t; }
    }
}

__global__ void k_rowptr(const int* __restrict__ deg, const int* __restrict__ bsum,
                         int* __restrict__ row_ptr) {
    __shared__ int sm[256];
    int i = blockIdx.x * 256 + threadIdx.x;
    int v = (i < N_NODES) ? deg[i] : 0;
    sm[threadIdx.x] = v;
    __syncthreads();
    for (int s = 1; s < 256; s <<= 1) {
        int t = (threadIdx.x >= (unsigned)s) ? sm[threadIdx.x - s] : 0;
        __syncthreads();
        sm[threadIdx.x] += t;
        __syncthreads();
    }
    if (i < N_NODES) row_ptr[i] = bsum[blockIdx.x] + sm[threadIdx.x] - v;  // exclusive
}

__global__ void k_scatter(const int* __restrict__ src, const int* __restrict__ dst,
                          const int* __restrict__ row_ptr, int* __restrict__ cursor,
                          int* __restrict__ csr_src) {
    int e = blockIdx.x * 256 + threadIdx.x;
    if (e < N_EDGES) {
        int d = dst[e];
        int pos = atomicAdd(&cursor[d], 1);
        csr_src[row_ptr[d] + pos] = src[e];
    }
}

// h0h = f16(feat @ W_in + b_in)   one wave per node, lane = out col
__global__ __launch_bounds__(256) void k_in_gemm(const float* __restrict__ feat,
                                                 const float* __restrict__ W,
                                                 const float* __restrict__ b,
                                                 u16* __restrict__ h0h) {
    __shared__ float sW[IN_DIM * HID];
    __shared__ float sb[HID];
    int t = threadIdx.x;
    for (int i = t; i < IN_DIM * HID; i += 256) sW[i] = W[i];
    if (t < HID) sb[t] = b[t];
    __syncthreads();
    int wid = (blockIdx.x * 256 + t) >> 6;   // node
    int lane = t & 63;
    const float* f = feat + wid * IN_DIM;
    float acc = sb[lane];
    #pragma unroll
    for (int k = 0; k < IN_DIM; k++) acc += f[k] * sW[k * HID + lane];
    h0h[wid * HID + lane] = f2h(acc);
}

// ---------------- per-layer kernels ----------------

// fsfd[N][512] (f16) = [h|h0] @ Wcat + bcat via MFMA 16x16x32 f16.
// Block = 4 waves; each wave computes 2 row-tiles (32 rows), 4 col-groups of 128.
#define ST_STRIDE 152   // u16 per staged C row (304 B: 16B-aligned, bank-spread)
__global__ __launch_bounds__(256) void k_gemm_mfma(const u16* __restrict__ hb,
                                                   const u16* __restrict__ h0b,
                                                   const u16* __restrict__ Wpack,
                                                   const float* __restrict__ bcat,
                                                   u16* __restrict__ fsfd) {
    __shared__ u16 smem[16384];   // 32 KB: W-group fragments, then reused for C staging
    int tid = threadIdx.x;
    int l = tid & 63, w = tid >> 6;
    int lr = l & 15, lg = l >> 4;
    int wave_gid = blockIdx.x * 4 + w;
    size_t rbase = (size_t)wave_gid * 32;
    u16* myst = smem + w * 4096;              // per-wave C staging slice (16*152=2432 used)

    for (int g = 0; g < 4; g++) {
        __syncthreads();   // prior group's staging reads done before W overwrite
        {
            const f16x8* src = (const f16x8*)(Wpack) + g * 2048;
            f16x8* dst = (f16x8*)smem;
            #pragma unroll
            for (int it = 0; it < 8; it++) dst[it * 256 + tid] = src[it * 256 + tid];
        }
        __syncthreads();

        f32x4 acc[2][8];
        #pragma unroll
        for (int rt = 0; rt < 2; rt++)
            #pragma unroll
            for (int nt = 0; nt < 8; nt++) acc[rt][nt] = (f32x4){0.f, 0.f, 0.f, 0.f};

        #pragma unroll
        for (int kt = 0; kt < 4; kt++) {
            const u16* A = (kt < 2) ? hb : h0b;
            int koff = (kt & 1) * 32 + lg * 8;
            f16x8 a0, a1;
            {
                size_t r0 = rbase + lr;        // tile 0
                size_t r1 = rbase + 16 + lr;   // tile 1
                if (r0 >= N_NODES) r0 = 0;
                if (r1 >= N_NODES) r1 = 0;
                a0 = *(const f16x8*)(A + r0 * HID + koff);
                a1 = *(const f16x8*)(A + r1 * HID + koff);
            }
            #pragma unroll
            for (int nt = 0; nt < 8; nt++) {
                f16x8 bfr = *(const f16x8*)(smem + nt * 2048 + kt * 512 + l * 8);
                acc[0][nt] = __builtin_amdgcn_mfma_f32_16x16x32_f16(a0, bfr, acc[0][nt], 0, 0, 0);
                acc[1][nt] = __builtin_amdgcn_mfma_f32_16x16x32_f16(a1, bfr, acc[1][nt], 0, 0, 0);
            }
        }
        __syncthreads();   // all waves done reading W before staging overwrites it

        // C/D layout: acc[rt][nt][j] = C[rbase + rt*16 + lg*4 + j][g*128 + nt*16 + lr]
        #pragma unroll
        for (int rt = 0; rt < 2; rt++) {
            size_t row0 = rbase + rt * 16;
            if (row0 >= N_NODES) break;
            #pragma unroll
            for (int nt = 0; nt < 8; nt++) {
                float bv = bcat[g * 128 + nt * 16 + lr];
                #pragma unroll
                for (int j = 0; j < 4; j++)
                    myst[(lg * 4 + j) * ST_STRIDE + nt * 16 + lr] = f2h(acc[rt][nt][j] + bv);
            }
            #pragma unroll
            for (int j = 0; j < 4; j++) {
                int rloc = j * 4 + lg;
                f16x8 v = *(const f16x8*)(myst + rloc * ST_STRIDE + lr * 8);
                *(f16x8*)(fsfd + (row0 + rloc) * 512 + g * 128 + lr * 8) = v;
            }
        }
    }
}

// Per dst node: online segment-softmax + weighted aggregation + tanh-headsum.
// One wave per node, 4 edge-groups x 16 lanes, TWO independent online states
// per group (edges ==g mod 8 and ==g+4 mod 8) for 2x memory-level parallelism
// and half the serial chain length. Lane ll covers row elements ll*16..+15.
__global__ __launch_bounds__(256) void k_edge(const u16* __restrict__ fsfd,
                                              const u16* __restrict__ an_h,
                                              const int* __restrict__ row_ptr,
                                              const int* __restrict__ deg,
                                              const int* __restrict__ csr_src,
                                              u16* __restrict__ h) {
    int wid = (blockIdx.x * 256 + threadIdx.x) >> 6;   // node (grid exact)
    int lane = threadIdx.x & 63;
    int g  = lane >> 4;       // edge group
    int ll = lane & 15;       // element slot
    const size_t ebase = (size_t)ll * 16;

    h2 an[8], fdh[8];
    {
        const uint4* ap = (const uint4*)(an_h + ebase);
        uint4 a0 = ap[0], a1 = ap[1];
        unsigned aw[8] = {a0.x, a0.y, a0.z, a0.w, a1.x, a1.y, a1.z, a1.w};
        __builtin_memcpy(an, aw, 32);
        const uint4* fp = (const uint4*)(fsfd + (size_t)wid * 512 + 256 + ebase);
        uint4 b0 = fp[0], b1 = fp[1];
        unsigned fw[8] = {b0.x, b0.y, b0.z, b0.w, b1.x, b1.y, b1.z, b1.w};
        __builtin_memcpy(fdh, fw, 32);
    }
    const h2 slope2 = {(_Float16)NEG_SLOPE, (_Float16)NEG_SLOPE};

    float mA = -3.0e38f, mB = -3.0e38f, dnA = 0.f, dnB = 0.f;
    h2 aggA[8], aggB[8];
    #pragma unroll
    for (int q = 0; q < 8; q++) {
        aggA[q] = (h2){(_Float16)0.f, (_Float16)0.f};
        aggB[q] = (h2){(_Float16)0.f, (_Float16)0.f};
    }

    int r0 = row_ptr[wid], dg = deg[wid];
    for (int i = g; i < dg; i += 8) {
        int iB = i + 4;
        bool hB = iB < dg;                       // uniform within each 16-lane group
        int sA = csr_src[r0 + i];
        int sB = csr_src[r0 + (hB ? iB : i)];
        const uint4* PA = (const uint4*)(fsfd + (size_t)sA * 512 + ebase);
        const uint4* PB = (const uint4*)(fsfd + (size_t)sB * 512 + ebase);
        uint4 A0 = PA[0], A1 = PA[1];            // both gathers in flight together
        uint4 B0 = PB[0], B1 = PB[1];

        h2 fA[8];
        {
            unsigned fw[8] = {A0.x, A0.y, A0.z, A0.w, A1.x, A1.y, A1.z, A1.w};
            __builtin_memcpy(fA, fw, 32);
        }
        float p0 = 0.f, p1 = 0.f;
        #pragma unroll
        for (int q = 0; q < 8; q += 2) {
            h2 e0 = fA[q] + fdh[q];
            h2 e1 = fA[q+1] + fdh[q+1];
            h2 l0 = __builtin_elementwise_max(e0, e0 * slope2);
            h2 l1 = __builtin_elementwise_max(e1, e1 * slope2);
            p0 = __builtin_amdgcn_fdot2(l0, an[q],   p0, false);
            p1 = __builtin_amdgcn_fdot2(l1, an[q+1], p1, false);
        }
        float p = p0 + p1;
        p += DPP_XOR1(p);
        p += DPP_XOR2(p);
        float nm = fmaxf(mA, p);
        float rs = exp2f(mA - nm);
        float c  = exp2f(p - nm);
        h2 rs2 = bcast_h2(rs), c2 = bcast_h2(c);
        #pragma unroll
        for (int q = 0; q < 8; q++) aggA[q] = aggA[q] * rs2 + fA[q] * c2;
        dnA = fmaf(dnA, rs, c);
        mA = nm;

        if (hB) {
            h2 fB[8];
            {
                unsigned fw[8] = {B0.x, B0.y, B0.z, B0.w, B1.x, B1.y, B1.z, B1.w};
                __builtin_memcpy(fB, fw, 32);
            }
            float q0 = 0.f, q1 = 0.f;
            #pragma unroll
            for (int q = 0; q < 8; q += 2) {
                h2 e0 = fB[q] + fdh[q];
                h2 e1 = fB[q+1] + fdh[q+1];
                h2 l0 = __builtin_elementwise_max(e0, e0 * slope2);
                h2 l1 = __builtin_elementwise_max(e1, e1 * slope2);
                q0 = __builtin_amdgcn_fdot2(l0, an[q],   q0, false);
                q1 = __builtin_amdgcn_fdot2(l1, an[q+1], q1, false);
            }
            float pB = q0 + q1;
            pB += DPP_XOR1(pB);
            pB += DPP_XOR2(pB);
            float nmB = fmaxf(mB, pB);
            float rsB = exp2f(mB - nmB);
            float cB  = exp2f(pB - nmB);
            h2 rsB2 = bcast_h2(rsB), cB2 = bcast_h2(cB);
            #pragma unroll
            for (int q = 0; q < 8; q++) aggB[q] = aggB[q] * rsB2 + fB[q] * cB2;
            dnB = fmaf(dnB, rsB, cB);
            mB = nmB;
        }
    }

    // merge state B into A (in-lane)
    float m, denom;
    h2 agg[8];
    {
        m = fmaxf(mA, mB);
        float sA = exp2f(mA - m), sB = exp2f(mB - m);
        denom = dnA * sA + dnB * sB;
        h2 sA2 = bcast_h2(sA), sB2 = bcast_h2(sB);
        #pragma unroll
        for (int q = 0; q < 8; q++) agg[q] = aggA[q] * sA2 + aggB[q] * sB2;
    }

    // cross-group merge: global max, scale once, then butterfly-sum
    {
        float mm = fmaxf(m, __shfl_xor(m, 16));
        mm = fmaxf(mm, __shfl_xor(mm, 32));
        float sc = exp2f(m - mm);
        denom *= sc;
        h2 sc2 = bcast_h2(sc);
        #pragma unroll
        for (int q = 0; q < 8; q++) agg[q] = agg[q] * sc2;
        denom += __shfl_xor(denom, 16);
        denom += __shfl_xor(denom, 32);
        #pragma unroll
        for (int q = 0; q < 8; q++) {
            agg[q] = agg[q] + shfl_h2(agg[q], 16);
            agg[q] = agg[q] + shfl_h2(agg[q], 32);
        }
    }

    float inv = denom > 0.f ? __builtin_amdgcn_rcpf(denom) : 0.f;
    float inv2 = inv * 2.885390082f;   // * 2*log2(e) for tanh via exp2

    // group g handles elements q = 2g, 2g+1 (4 scalars); static selects, no scratch
    h2 x0 = (g & 2) ? ((g & 1) ? agg[6] : agg[4]) : ((g & 1) ? agg[2] : agg[0]);
    h2 x1 = (g & 2) ? ((g & 1) ? agg[7] : agg[5]) : ((g & 1) ? agg[3] : agg[1]);
    float t[4] = {(float)x0[0], (float)x0[1], (float)x1[0], (float)x1[1]};
    #pragma unroll
    for (int j = 0; j < 4; j++) {
        float E = exp2f(t[j] * inv2);          // tanh(y) = 1 - 2/(e^{2y}+1)
        float r = __builtin_amdgcn_rcpf(E + 1.f);
        float v = fmaf(-2.f, r, 1.f);
        v += __shfl_xor(v, 4);                 // sum over the 4 heads
        v += __shfl_xor(v, 8);
        t[j] = v;
    }
    if (ll < 4) {
        // lane (g, ll) holds dims d = ll*16 + g*4 + {0..3}
        uint2 o;
        o.x = (unsigned)f2h(t[0]) | ((unsigned)f2h(t[1]) << 16);
        o.y = (unsigned)f2h(t[2]) | ((unsigned)f2h(t[3]) << 16);
        *(uint2*)(h + (size_t)wid * 64 + ll * 16 + g * 4) = o;
    }
}

// ---------------- readout ----------------

__global__ __launch_bounds__(256) void k_readout(const u16* __restrict__ h,
                                                 const int* __restrict__ graph_ids,
                                                 const int* __restrict__ is_root,
                                                 float* __restrict__ hg) {
    int wid = (blockIdx.x * 256 + threadIdx.x) >> 6;
    int lane = threadIdx.x & 63;
    if (is_root[wid]) {
        int g = graph_ids[wid];
        atomicAdd(&hg[g * HID + lane], h2f_lo(h[(size_t)wid * HID + lane]));
    }
}

__global__ void k_out_gemm(const float* __restrict__ hg, const float* __restrict__ W,
                           const float* __restrict__ b, float* __restrict__ out) {
    int i = blockIdx.x * 256 + threadIdx.x;
    if (i >= NGRAPH * OUT_DIM) return;
    int g = i >> 5, o = i & 31;
    float acc = b[o];
    #pragma unroll
    for (int k = 0; k < HID; k++) acc += hg[g * HID + k] * W[k * OUT_DIM + o];
    out[i] = acc;
}

// ---------------- host ----------------

extern "C" void kernel_launch(void* const* d_in, const int* in_sizes, int n_in,
                              void* d_out, int out_size, void* d_ws, size_t ws_size,
                              hipStream_t stream) {
    const float* feat      = (const float*)d_in[0];
    const int*   src       = (const int*)d_in[1];
    const int*   dst       = (const int*)d_in[2];
    const int*   graph_ids = (const int*)d_in[3];
    const int*   is_root   = (const int*)d_in[4];
    const float* W_in      = (const float*)d_in[5];
    const float* b_in      = (const float*)d_in[6];
    const float* W_src     = (const float*)d_in[7];
    const float* b_src     = (const float*)d_in[8];
    const float* W_dst     = (const float*)d_in[9];
    const float* b_dst     = (const float*)d_in[10];
    const float* attn      = (const float*)d_in[11];
    const float* W_out     = (const float*)d_in[12];
    const float* b_out     = (const float*)d_in[13];
    float* out = (float*)d_out;

    char* base = (char*)d_ws;
    size_t off = 0;
    auto carve = [&](size_t bytes) -> char* {
        char* p = base + off;
        off = (off + bytes + 255) & ~(size_t)255;
        return p;
    };
    u16*   h0b     = (u16*)carve((size_t)N_NODES * HID * 2);
    u16*   hb      = (u16*)carve((size_t)N_NODES * HID * 2);
    u16*   fsfd    = (u16*)carve((size_t)N_NODES * 512 * 2);
    u16*   Wpack   = (u16*)carve(128 * 512 * 2);
    float* bcat    = (float*)carve(512 * 4);
    u16*   an_h    = (u16*)carve(256 * 2);
    int*   csr_src = (int*)carve((size_t)N_EDGES * 4);
    int*   row_ptr = (int*)carve((size_t)N_NODES * 4);
    int*   bsum    = (int*)carve(SCAN_BLOCKS * 4);
    char*  zero0   = carve(0);
    int*   deg     = (int*)carve((size_t)N_NODES * 4);
    int*   cursor  = (int*)carve((size_t)N_NODES * 4);
    float* hg      = (float*)carve((size_t)NGRAPH * HID * 4);
    char*  zero1   = base + off;
    if (off > ws_size) return;  // workspace too small -> fail loudly

    hipMemsetAsync(zero0, 0, (size_t)(zero1 - zero0), stream);

    // graph prep
    k_build_wpack<<<256, 256, 0, stream>>>(W_src, b_src, W_dst, b_dst, attn, Wpack, bcat, an_h);
    k_hist<<<(N_EDGES + 255) / 256, 256, 0, stream>>>(dst, deg);
    k_blocksum<<<SCAN_BLOCKS, 256, 0, stream>>>(deg, bsum);
    k_scanbsum<<<1, 64, 0, stream>>>(bsum);
    k_rowptr<<<SCAN_BLOCKS, 256, 0, stream>>>(deg, bsum, row_ptr);
    k_scatter<<<(N_EDGES + 255) / 256, 256, 0, stream>>>(src, dst, row_ptr, cursor, csr_src);

    // input projection
    k_in_gemm<<<N_NODES / 4, 256, 0, stream>>>(feat, W_in, b_in, h0b);

    const int gemm_grid = (N_NODES + 127) / 128;   // 391 blocks (4 waves x 32 rows)
    for (int layer = 0; layer < NUM_LAYERS; layer++) {
        const u16* hcur = (layer == 0) ? h0b : hb;
        k_gemm_mfma<<<gemm_grid, 256, 0, stream>>>(hcur, h0b, Wpack, bcat, fsfd);
        k_edge<<<N_NODES / 4, 256, 0, stream>>>(fsfd, an_h, row_ptr, deg, csr_src, hb);
    }

    k_readout<<<N_NODES / 4, 256, 0, stream>>>(hb, graph_ids, is_root, hg);
    k_out_gemm<<<(NGRAPH * OUT_DIM + 255) / 256, 256, 0, stream>>>(hg, W_out, b_out, out);
}

// Round 8
// 961.812 us; speedup vs baseline: 1.0292x; 1.0292x over previous
//
#include <hip/hip_runtime.h>
#include <math.h>

#define N_NODES 50000
#define N_EDGES 800000
#define IN_DIM  16
#define HID     64
#define NH      4
#define NGRAPH  128
#define OUT_DIM 32
#define NUM_LAYERS 8
#define NEG_SLOPE 0.2f

#define SCAN_BLOCKS ((N_NODES + 255) / 256)   // 196

typedef unsigned short u16;
typedef unsigned char  u8;
typedef _Float16 h2   __attribute__((ext_vector_type(2)));
typedef _Float16 f16x8 __attribute__((ext_vector_type(8)));
typedef float f32x2 __attribute__((ext_vector_type(2)));
typedef __attribute__((ext_vector_type(4))) float f32x4;

static __device__ __forceinline__ u16 f2h(float f) {
    _Float16 h = (_Float16)f; u16 r; __builtin_memcpy(&r, &h, 2); return r;
}
static __device__ __forceinline__ float h2f_lo(unsigned w) {
    _Float16 h; u16 u = (u16)w; __builtin_memcpy(&h, &u, 2); return (float)h;
}
static __device__ __forceinline__ h2 shfl_h2(h2 v, int mask) {
    int i; __builtin_memcpy(&i, &v, 4); i = __shfl_xor(i, mask);
    h2 r; __builtin_memcpy(&r, &i, 4); return r;
}
static __device__ __forceinline__ h2 bcast_h2(float f) {
    _Float16 h = (_Float16)f; h2 r; r[0] = h; r[1] = h; return r;
}
// 2 fp8 (e4m3, low 16 bits of w) -> 2 f16 (via native v2f32 from cvt_pk_f32_fp8)
static __device__ __forceinline__ h2 fp8x2_to_h2(unsigned w) {
    f32x2 f = __builtin_amdgcn_cvt_pk_f32_fp8((int)w, false);
    h2 r; r[0] = (_Float16)f[0]; r[1] = (_Float16)f[1]; return r;
}

// DPP lane-xor within quads (VALU-only cross-lane reduce)
#define DPP_XOR1(x) __uint_as_float((unsigned)__builtin_amdgcn_update_dpp(0, (int)__float_as_uint(x), 0xB1, 0xF, 0xF, true))
#define DPP_XOR2(x) __uint_as_float((unsigned)__builtin_amdgcn_update_dpp(0, (int)__float_as_uint(x), 0x4E, 0xF, 0xF, true))

// ---------------- setup kernels ----------------

// Pack Wcat=[W_src|W_dst] (fp32 [128][512]) into MFMA-fragment-ordered f16:
// Wpack[((nt*4+kt)*64 + l)*8 + i] = Wcat[kt*32 + (l>>4)*8 + i][nt*16 + (l&15)]
// Also bcat[512] f32 and an_h[256] = f16(attn * log2e).
__global__ void k_build_wpack(const float* __restrict__ Wsrc, const float* __restrict__ bsrc,
                              const float* __restrict__ Wdst, const float* __restrict__ bdst,
                              const float* __restrict__ attn,
                              u16* __restrict__ Wpack, float* __restrict__ bcat,
                              u16* __restrict__ an_h) {
    int tid = blockIdx.x * 256 + threadIdx.x;   // 0..65535
    int i = tid & 7;
    int l = (tid >> 3) & 63;
    int rest = tid >> 9;          // 0..127
    int kt = rest & 3;
    int nt = rest >> 2;           // 0..31
    int k = kt * 32 + (l >> 4) * 8 + i;      // 0..127
    int col = nt * 16 + (l & 15);            // 0..511
    float v = (col < 256) ? Wsrc[k * 256 + col] : Wdst[k * 256 + (col - 256)];
    Wpack[tid] = f2h(v);
    if (tid < 512) bcat[tid] = (tid < 256) ? bsrc[tid] : bdst[tid - 256];
    if (tid < 256) an_h[tid] = f2h(attn[tid] * 1.44269504f);   // fold log2(e)
}

__global__ void k_hist(const int* __restrict__ dst, int* __restrict__ deg) {
    int e = blockIdx.x * 256 + threadIdx.x;
    if (e < N_EDGES) atomicAdd(&deg[dst[e]], 1);
}

__global__ void k_blocksum(const int* __restrict__ deg, int* __restrict__ bsum) {
    __shared__ int sm[256];
    int i = blockIdx.x * 256 + threadIdx.x;
    sm[threadIdx.x] = (i < N_NODES) ? deg[i] : 0;
    __syncthreads();
    for (int s = 128; s > 0; s >>= 1) {
        if (threadIdx.x < s) sm[threadIdx.x] += sm[threadIdx.x + s];
        __syncthreads();
    }
    if (threadIdx.x == 0) bsum[blockIdx.x] = sm[0];
}

__global__ void k_scanbsum(int* __restrict__ bsum) {
    if (threadIdx.x == 0 && blockIdx.x == 0) {
        int acc = 0;
        for (int b = 0; b < SCAN_BLOCKS; b++) { int t = bsum[b]; bsum[b] = acc; acc += t; }
    }
}

__global__ void k_rowptr(const int* __restrict__ deg, const int* __restrict__ bsum,
                         int* __restrict__ row_ptr) {
    __shared__ int sm[256];
    int i = blockIdx.x * 256 + threadIdx.x;
    int v = (i < N_NODES) ? deg[i] : 0;
    sm[threadIdx.x] = v;
    __syncthreads();
    for (int s = 1; s < 256; s <<= 1) {
        int t = (threadIdx.x >= (unsigned)s) ? sm[threadIdx.x - s] : 0;
        __syncthreads();
        sm[threadIdx.x] += t;
        __syncthreads();
    }
    if (i < N_NODES) row_ptr[i] = bsum[blockIdx.x] + sm[threadIdx.x] - v;  // exclusive
}

__global__ void k_scatter(const int* __restrict__ src, const int* __restrict__ dst,
                          const int* __restrict__ row_ptr, int* __restrict__ cursor,
                          int* __restrict__ csr_src) {
    int e = blockIdx.x * 256 + threadIdx.x;
    if (e < N_EDGES) {
        int d = dst[e];
        int pos = atomicAdd(&cursor[d], 1);
        csr_src[row_ptr[d] + pos] = src[e];
    }
}

// h0h = f16(feat @ W_in + b_in)   one wave per node, lane = out col
__global__ __launch_bounds__(256) void k_in_gemm(const float* __restrict__ feat,
                                                 const float* __restrict__ W,
                                                 const float* __restrict__ b,
                                                 u16* __restrict__ h0h) {
    __shared__ float sW[IN_DIM * HID];
    __shared__ float sb[HID];
    int t = threadIdx.x;
    for (int i = t; i < IN_DIM * HID; i += 256) sW[i] = W[i];
    if (t < HID) sb[t] = b[t];
    __syncthreads();
    int wid = (blockIdx.x * 256 + t) >> 6;   // node
    int lane = t & 63;
    const float* f = feat + wid * IN_DIM;
    float acc = sb[lane];
    #pragma unroll
    for (int k = 0; k < IN_DIM; k++) acc += f[k] * sW[k * HID + lane];
    h0h[wid * HID + lane] = f2h(acc);
}

// ---------------- per-layer kernels ----------------

// fs8[N][256] (fp8 e4m3) + fdh[N][256] (f16) = [h|h0] @ Wcat + bcat via MFMA.
// Block = 4 waves; each wave computes 2 row-tiles (32 rows), 4 col-groups of 128.
// Groups 0,1 -> fs (fp8); groups 2,3 -> fd (f16).
#define ST_STRIDE 152   // u16 per staged C row (304 B: 16B-aligned, bank-spread)
__global__ __launch_bounds__(256) void k_gemm_mfma(const u16* __restrict__ hb,
                                                   const u16* __restrict__ h0b,
                                                   const u16* __restrict__ Wpack,
                                                   const float* __restrict__ bcat,
                                                   u8* __restrict__ fs8,
                                                   u16* __restrict__ fdh) {
    __shared__ u16 smem[16384];   // 32 KB: W-group fragments, then reused for C staging
    int tid = threadIdx.x;
    int l = tid & 63, w = tid >> 6;
    int lr = l & 15, lg = l >> 4;
    int wave_gid = blockIdx.x * 4 + w;
    size_t rbase = (size_t)wave_gid * 32;
    u16* myst = smem + w * 4096;              // per-wave C staging slice (16*152=2432 used)

    for (int g = 0; g < 4; g++) {
        __syncthreads();   // prior group's staging reads done before W overwrite
        {
            const f16x8* src = (const f16x8*)(Wpack) + g * 2048;
            f16x8* dst = (f16x8*)smem;
            #pragma unroll
            for (int it = 0; it < 8; it++) dst[it * 256 + tid] = src[it * 256 + tid];
        }
        __syncthreads();

        f32x4 acc[2][8];
        #pragma unroll
        for (int rt = 0; rt < 2; rt++)
            #pragma unroll
            for (int nt = 0; nt < 8; nt++) acc[rt][nt] = (f32x4){0.f, 0.f, 0.f, 0.f};

        #pragma unroll
        for (int kt = 0; kt < 4; kt++) {
            const u16* A = (kt < 2) ? hb : h0b;
            int koff = (kt & 1) * 32 + lg * 8;
            f16x8 a0, a1;
            {
                size_t r0 = rbase + lr;        // tile 0
                size_t r1 = rbase + 16 + lr;   // tile 1
                if (r0 >= N_NODES) r0 = 0;
                if (r1 >= N_NODES) r1 = 0;
                a0 = *(const f16x8*)(A + r0 * HID + koff);
                a1 = *(const f16x8*)(A + r1 * HID + koff);
            }
            #pragma unroll
            for (int nt = 0; nt < 8; nt++) {
                f16x8 bfr = *(const f16x8*)(smem + nt * 2048 + kt * 512 + l * 8);
                acc[0][nt] = __builtin_amdgcn_mfma_f32_16x16x32_f16(a0, bfr, acc[0][nt], 0, 0, 0);
                acc[1][nt] = __builtin_amdgcn_mfma_f32_16x16x32_f16(a1, bfr, acc[1][nt], 0, 0, 0);
            }
        }
        __syncthreads();   // all waves done reading W before staging overwrites it

        // C/D layout: acc[rt][nt][j] = C[rbase + rt*16 + lg*4 + j][g*128 + nt*16 + lr]
        #pragma unroll
        for (int rt = 0; rt < 2; rt++) {
            size_t row0 = rbase + rt * 16;
            if (row0 >= N_NODES) break;
            #pragma unroll
            for (int nt = 0; nt < 8; nt++) {
                float bv = bcat[g * 128 + nt * 16 + lr];
                #pragma unroll
                for (int j = 0; j < 4; j++)
                    myst[(lg * 4 + j) * ST_STRIDE + nt * 16 + lr] = f2h(acc[rt][nt][j] + bv);
            }
            #pragma unroll
            for (int j = 0; j < 4; j++) {
                int rloc = j * 4 + lg;
                f16x8 v = *(const f16x8*)(myst + rloc * ST_STRIDE + lr * 8);
                if (g < 2) {
                    // convert 8 f16 -> 8 fp8 bytes, coalesced uint2 store
                    int p0 = __builtin_amdgcn_cvt_pk_fp8_f32((float)v[0], (float)v[1], 0, false);
                    int p1 = __builtin_amdgcn_cvt_pk_fp8_f32((float)v[2], (float)v[3], 0, false);
                    int p2 = __builtin_amdgcn_cvt_pk_fp8_f32((float)v[4], (float)v[5], 0, false);
                    int p3 = __builtin_amdgcn_cvt_pk_fp8_f32((float)v[6], (float)v[7], 0, false);
                    uint2 o8;
                    o8.x = (unsigned)(p0 & 0xffff) | ((unsigned)p1 << 16);
                    o8.y = (unsigned)(p2 & 0xffff) | ((unsigned)p3 << 16);
                    *(uint2*)(fs8 + (row0 + rloc) * 256 + g * 128 + lr * 8) = o8;
                } else {
                    *(f16x8*)(fdh + (row0 + rloc) * 256 + (g - 2) * 128 + lr * 8) = v;
                }
            }
        }
    }
}

// Per dst node: online segment-softmax + weighted aggregation + tanh-headsum.
// One wave per node, 4 edge-groups x 16 lanes, TWO independent online states per
// group. Gather = ONE dwordx4/edge (fp8 row, 256 B), cvt to packed f16 pipeline.
__global__ __launch_bounds__(256) void k_edge(const u8* __restrict__ fs8,
                                              const u16* __restrict__ fdh,
                                              const u16* __restrict__ an_h,
                                              const int* __restrict__ row_ptr,
                                              const int* __restrict__ deg,
                                              const int* __restrict__ csr_src,
                                              u16* __restrict__ h) {
    int wid = (blockIdx.x * 256 + threadIdx.x) >> 6;   // node (grid exact)
    int lane = threadIdx.x & 63;
    int g  = lane >> 4;       // edge group
    int ll = lane & 15;       // element slot
    const size_t ebase = (size_t)ll * 16;

    h2 an[8], fdhv[8];
    {
        const uint4* ap = (const uint4*)(an_h + ebase);
        uint4 a0 = ap[0], a1 = ap[1];
        unsigned aw[8] = {a0.x, a0.y, a0.z, a0.w, a1.x, a1.y, a1.z, a1.w};
        __builtin_memcpy(an, aw, 32);
        const uint4* fp = (const uint4*)(fdh + (size_t)wid * 256 + ebase);
        uint4 b0 = fp[0], b1 = fp[1];
        unsigned fw[8] = {b0.x, b0.y, b0.z, b0.w, b1.x, b1.y, b1.z, b1.w};
        __builtin_memcpy(fdhv, fw, 32);
    }
    const h2 slope2 = {(_Float16)NEG_SLOPE, (_Float16)NEG_SLOPE};

    float mA = -3.0e38f, mB = -3.0e38f, dnA = 0.f, dnB = 0.f;
    h2 aggA[8], aggB[8];
    #pragma unroll
    for (int q = 0; q < 8; q++) {
        aggA[q] = (h2){(_Float16)0.f, (_Float16)0.f};
        aggB[q] = (h2){(_Float16)0.f, (_Float16)0.f};
    }

    int r0 = row_ptr[wid], dg = deg[wid];
    for (int i = g; i < dg; i += 8) {
        int iB = i + 4;
        bool hB = iB < dg;                       // uniform within each 16-lane group
        int sA = csr_src[r0 + i];
        int sB = csr_src[r0 + (hB ? iB : i)];
        uint4 A = *(const uint4*)(fs8 + (size_t)sA * 256 + ebase);   // 16 fp8
        uint4 B = *(const uint4*)(fs8 + (size_t)sB * 256 + ebase);

        h2 fA[8];
        {
            unsigned d[4] = {A.x, A.y, A.z, A.w};
            #pragma unroll
            for (int q = 0; q < 4; q++) {
                fA[2*q]   = fp8x2_to_h2(d[q] & 0xffffu);
                fA[2*q+1] = fp8x2_to_h2(d[q] >> 16);
            }
        }
        float p0 = 0.f, p1 = 0.f;
        #pragma unroll
        for (int q = 0; q < 8; q += 2) {
            h2 e0 = fA[q] + fdhv[q];
            h2 e1 = fA[q+1] + fdhv[q+1];
            h2 l0 = __builtin_elementwise_max(e0, e0 * slope2);
            h2 l1 = __builtin_elementwise_max(e1, e1 * slope2);
            p0 = __builtin_amdgcn_fdot2(l0, an[q],   p0, false);
            p1 = __builtin_amdgcn_fdot2(l1, an[q+1], p1, false);
        }
        float p = p0 + p1;
        p += DPP_XOR1(p);
        p += DPP_XOR2(p);
        float nm = fmaxf(mA, p);
        float rs = exp2f(mA - nm);
        float c  = exp2f(p - nm);
        h2 rs2 = bcast_h2(rs), c2 = bcast_h2(c);
        #pragma unroll
        for (int q = 0; q < 8; q++) aggA[q] = aggA[q] * rs2 + fA[q] * c2;
        dnA = fmaf(dnA, rs, c);
        mA = nm;

        if (hB) {
            h2 fB[8];
            {
                unsigned d[4] = {B.x, B.y, B.z, B.w};
                #pragma unroll
                for (int q = 0; q < 4; q++) {
                    fB[2*q]   = fp8x2_to_h2(d[q] & 0xffffu);
                    fB[2*q+1] = fp8x2_to_h2(d[q] >> 16);
                }
            }
            float q0 = 0.f, q1 = 0.f;
            #pragma unroll
            for (int q = 0; q < 8; q += 2) {
                h2 e0 = fB[q] + fdhv[q];
                h2 e1 = fB[q+1] + fdhv[q+1];
                h2 l0 = __builtin_elementwise_max(e0, e0 * slope2);
                h2 l1 = __builtin_elementwise_max(e1, e1 * slope2);
                q0 = __builtin_amdgcn_fdot2(l0, an[q],   q0, false);
                q1 = __builtin_amdgcn_fdot2(l1, an[q+1], q1, false);
            }
            float pB = q0 + q1;
            pB += DPP_XOR1(pB);
            pB += DPP_XOR2(pB);
            float nmB = fmaxf(mB, pB);
            float rsB = exp2f(mB - nmB);
            float cB  = exp2f(pB - nmB);
            h2 rsB2 = bcast_h2(rsB), cB2 = bcast_h2(cB);
            #pragma unroll
            for (int q = 0; q < 8; q++) aggB[q] = aggB[q] * rsB2 + fB[q] * cB2;
            dnB = fmaf(dnB, rsB, cB);
            mB = nmB;
        }
    }

    // merge state B into A (in-lane)
    float m, denom;
    h2 agg[8];
    {
        m = fmaxf(mA, mB);
        float sA = exp2f(mA - m), sB = exp2f(mB - m);
        denom = dnA * sA + dnB * sB;
        h2 sA2 = bcast_h2(sA), sB2 = bcast_h2(sB);
        #pragma unroll
        for (int q = 0; q < 8; q++) agg[q] = aggA[q] * sA2 + aggB[q] * sB2;
    }

    // cross-group merge: global max, scale once, then butterfly-sum
    {
        float mm = fmaxf(m, __shfl_xor(m, 16));
        mm = fmaxf(mm, __shfl_xor(mm, 32));
        float sc = exp2f(m - mm);
        denom *= sc;
        h2 sc2 = bcast_h2(sc);
        #pragma unroll
        for (int q = 0; q < 8; q++) agg[q] = agg[q] * sc2;
        denom += __shfl_xor(denom, 16);
        denom += __shfl_xor(denom, 32);
        #pragma unroll
        for (int q = 0; q < 8; q++) {
            agg[q] = agg[q] + shfl_h2(agg[q], 16);
            agg[q] = agg[q] + shfl_h2(agg[q], 32);
        }
    }

    float inv = denom > 0.f ? __builtin_amdgcn_rcpf(denom) : 0.f;
    float inv2 = inv * 2.885390082f;   // * 2*log2(e) for tanh via exp2

    // group g handles elements q = 2g, 2g+1 (4 scalars); static selects, no scratch
    h2 x0 = (g & 2) ? ((g & 1) ? agg[6] : agg[4]) : ((g & 1) ? agg[2] : agg[0]);
    h2 x1 = (g & 2) ? ((g & 1) ? agg[7] : agg[5]) : ((g & 1) ? agg[3] : agg[1]);
    float t[4] = {(float)x0[0], (float)x0[1], (float)x1[0], (float)x1[1]};
    #pragma unroll
    for (int j = 0; j < 4; j++) {
        float E = exp2f(t[j] * inv2);          // tanh(y) = 1 - 2/(e^{2y}+1)
        float r = __builtin_amdgcn_rcpf(E + 1.f);
        float v = fmaf(-2.f, r, 1.f);
        v += __shfl_xor(v, 4);                 // sum over the 4 heads
        v += __shfl_xor(v, 8);
        t[j] = v;
    }
    if (ll < 4) {
        // lane (g, ll) holds dims d = ll*16 + g*4 + {0..3}
        uint2 o;
        o.x = (unsigned)f2h(t[0]) | ((unsigned)f2h(t[1]) << 16);
        o.y = (unsigned)f2h(t[2]) | ((unsigned)f2h(t[3]) << 16);
        *(uint2*)(h + (size_t)wid * 64 + ll * 16 + g * 4) = o;
    }
}

// ---------------- readout ----------------

__global__ __launch_bounds__(256) void k_readout(const u16* __restrict__ h,
                                                 const int* __restrict__ graph_ids,
                                                 const int* __restrict__ is_root,
                                                 float* __restrict__ hg) {
    int wid = (blockIdx.x * 256 + threadIdx.x) >> 6;
    int lane = threadIdx.x & 63;
    if (is_root[wid]) {
        int g = graph_ids[wid];
        atomicAdd(&hg[g * HID + lane], h2f_lo(h[(size_t)wid * HID + lane]));
    }
}

__global__ void k_out_gemm(const float* __restrict__ hg, const float* __restrict__ W,
                           const float* __restrict__ b, float* __restrict__ out) {
    int i = blockIdx.x * 256 + threadIdx.x;
    if (i >= NGRAPH * OUT_DIM) return;
    int g = i >> 5, o = i & 31;
    float acc = b[o];
    #pragma unroll
    for (int k = 0; k < HID; k++) acc += hg[g * HID + k] * W[k * OUT_DIM + o];
    out[i] = acc;
}

// ---------------- host ----------------

extern "C" void kernel_launch(void* const* d_in, const int* in_sizes, int n_in,
                              void* d_out, int out_size, void* d_ws, size_t ws_size,
                              hipStream_t stream) {
    const float* feat      = (const float*)d_in[0];
    const int*   src       = (const int*)d_in[1];
    const int*   dst       = (const int*)d_in[2];
    const int*   graph_ids = (const int*)d_in[3];
    const int*   is_root   = (const int*)d_in[4];
    const float* W_in      = (const float*)d_in[5];
    const float* b_in      = (const float*)d_in[6];
    const float* W_src     = (const float*)d_in[7];
    const float* b_src     = (const float*)d_in[8];
    const float* W_dst     = (const float*)d_in[9];
    const float* b_dst     = (const float*)d_in[10];
    const float* attn      = (const float*)d_in[11];
    const float* W_out     = (const float*)d_in[12];
    const float* b_out     = (const float*)d_in[13];
    float* out = (float*)d_out;

    char* base = (char*)d_ws;
    size_t off = 0;
    auto carve = [&](size_t bytes) -> char* {
        char* p = base + off;
        off = (off + bytes + 255) & ~(size_t)255;
        return p;
    };
    u16*   h0b     = (u16*)carve((size_t)N_NODES * HID * 2);
    u16*   hb      = (u16*)carve((size_t)N_NODES * HID * 2);
    u8*    fs8     = (u8*)carve((size_t)N_NODES * 256);
    u16*   fdh     = (u16*)carve((size_t)N_NODES * 256 * 2);
    u16*   Wpack   = (u16*)carve(128 * 512 * 2);
    float* bcat    = (float*)carve(512 * 4);
    u16*   an_h    = (u16*)carve(256 * 2);
    int*   csr_src = (int*)carve((size_t)N_EDGES * 4);
    int*   row_ptr = (int*)carve((size_t)N_NODES * 4);
    int*   bsum    = (int*)carve(SCAN_BLOCKS * 4);
    char*  zero0   = carve(0);
    int*   deg     = (int*)carve((size_t)N_NODES * 4);
    int*   cursor  = (int*)carve((size_t)N_NODES * 4);
    float* hg      = (float*)carve((size_t)NGRAPH * HID * 4);
    char*  zero1   = base + off;
    if (off > ws_size) return;  // workspace too small -> fail loudly

    (void)hipMemsetAsync(zero0, 0, (size_t)(zero1 - zero0), stream);

    // graph prep
    k_build_wpack<<<256, 256, 0, stream>>>(W_src, b_src, W_dst, b_dst, attn, Wpack, bcat, an_h);
    k_hist<<<(N_EDGES + 255) / 256, 256, 0, stream>>>(dst, deg);
    k_blocksum<<<SCAN_BLOCKS, 256, 0, stream>>>(deg, bsum);
    k_scanbsum<<<1, 64, 0, stream>>>(bsum);
    k_rowptr<<<SCAN_BLOCKS, 256, 0, stream>>>(deg, bsum, row_ptr);
    k_scatter<<<(N_EDGES + 255) / 256, 256, 0, stream>>>(src, dst, row_ptr, cursor, csr_src);

    // input projection
    k_in_gemm<<<N_NODES / 4, 256, 0, stream>>>(feat, W_in, b_in, h0b);

    const int gemm_grid = (N_NODES + 127) / 128;   // 391 blocks (4 waves x 32 rows)
    for (int layer = 0; layer < NUM_LAYERS; layer++) {
        const u16* hcur = (layer == 0) ? h0b : hb;
        k_gemm_mfma<<<gemm_grid, 256, 0, stream>>>(hcur, h0b, Wpack, bcat, fs8, fdh);
        k_edge<<<N_NODES / 4, 256, 0, stream>>>(fs8, fdh, an_h, row_ptr, deg, csr_src, hb);
    }

    k_readout<<<N_NODES / 4, 256, 0, stream>>>(hb, graph_ids, is_root, hg);
    k_out_gemm<<<(NGRAPH * OUT_DIM + 255) / 256, 256, 0, stream>>>(hg, W_out, b_out, out);
}

// Round 10
// 824.086 us; speedup vs baseline: 1.2012x; 1.1671x over previous
//
#include <hip/hip_runtime.h>
#include <math.h>

#define N_NODES 50000
#define N_EDGES 800000
#define IN_DIM  16
#define HID     64
#define NH      4
#define NGRAPH  128
#define OUT_DIM 32
#define NUM_LAYERS 8
#define NEG_SLOPE 0.2f

#define SCAN_BLOCKS ((N_NODES + 255) / 256)   // 196

typedef unsigned short u16;
typedef unsigned char  u8;
typedef _Float16 h2   __attribute__((ext_vector_type(2)));
typedef _Float16 f16x8 __attribute__((ext_vector_type(8)));
typedef float f32x2 __attribute__((ext_vector_type(2)));
typedef __attribute__((ext_vector_type(4))) float f32x4;

static __device__ __forceinline__ u16 f2h(float f) {
    _Float16 h = (_Float16)f; u16 r; __builtin_memcpy(&r, &h, 2); return r;
}
static __device__ __forceinline__ float h2f_lo(unsigned w) {
    _Float16 h; u16 u = (u16)w; __builtin_memcpy(&h, &u, 2); return (float)h;
}
static __device__ __forceinline__ h2 shfl_h2(h2 v, int mask) {
    int i; __builtin_memcpy(&i, &v, 4); i = __shfl_xor(i, mask);
    h2 r; __builtin_memcpy(&r, &i, 4); return r;
}
static __device__ __forceinline__ h2 bcast_h2(float f) {
    _Float16 h = (_Float16)f; h2 r; r[0] = h; r[1] = h; return r;
}
// v_cvt_pkrtz_f16_f32 with a bit-cast to our h2 typedef (__fp16 vs _Float16 vec)
static __device__ __forceinline__ h2 pkrtz_h2(float a, float b) {
    auto v = __builtin_amdgcn_cvt_pkrtz(a, b);
    h2 r; __builtin_memcpy(&r, &v, 4); return r;
}

// DPP lane-xor within quads (VALU-only cross-lane reduce)
#define DPP_XOR1(x) __uint_as_float((unsigned)__builtin_amdgcn_update_dpp(0, (int)__float_as_uint(x), 0xB1, 0xF, 0xF, true))
#define DPP_XOR2(x) __uint_as_float((unsigned)__builtin_amdgcn_update_dpp(0, (int)__float_as_uint(x), 0x4E, 0xF, 0xF, true))

// ---------------- setup kernels ----------------

// Pack Wcat=[W_src|W_dst] (fp32 [128][512]) into MFMA-fragment-ordered f16:
// Wpack[((nt*4+kt)*64 + l)*8 + i] = Wcat[kt*32 + (l>>4)*8 + i][nt*16 + (l&15)]
// Also bcat[512] f32 and an_h[256] = f16(attn * log2e).
__global__ void k_build_wpack(const float* __restrict__ Wsrc, const float* __restrict__ bsrc,
                              const float* __restrict__ Wdst, const float* __restrict__ bdst,
                              const float* __restrict__ attn,
                              u16* __restrict__ Wpack, float* __restrict__ bcat,
                              u16* __restrict__ an_h) {
    int tid = blockIdx.x * 256 + threadIdx.x;   // 0..65535
    int i = tid & 7;
    int l = (tid >> 3) & 63;
    int rest = tid >> 9;          // 0..127
    int kt = rest & 3;
    int nt = rest >> 2;           // 0..31
    int k = kt * 32 + (l >> 4) * 8 + i;      // 0..127
    int col = nt * 16 + (l & 15);            // 0..511
    float v = (col < 256) ? Wsrc[k * 256 + col] : Wdst[k * 256 + (col - 256)];
    Wpack[tid] = f2h(v);
    if (tid < 512) bcat[tid] = (tid < 256) ? bsrc[tid] : bdst[tid - 256];
    if (tid < 256) an_h[tid] = f2h(attn[tid] * 1.44269504f);   // fold log2(e)
}

__global__ void k_hist(const int* __restrict__ dst, int* __restrict__ deg) {
    int e = blockIdx.x * 256 + threadIdx.x;
    if (e < N_EDGES) atomicAdd(&deg[dst[e]], 1);
}

__global__ void k_blocksum(const int* __restrict__ deg, int* __restrict__ bsum) {
    __shared__ int sm[256];
    int i = blockIdx.x * 256 + threadIdx.x;
    sm[threadIdx.x] = (i < N_NODES) ? deg[i] : 0;
    __syncthreads();
    for (int s = 128; s > 0; s >>= 1) {
        if (threadIdx.x < s) sm[threadIdx.x] += sm[threadIdx.x + s];
        __syncthreads();
    }
    if (threadIdx.x == 0) bsum[blockIdx.x] = sm[0];
}

__global__ void k_scanbsum(int* __restrict__ bsum) {
    if (threadIdx.x == 0 && blockIdx.x == 0) {
        int acc = 0;
        for (int b = 0; b < SCAN_BLOCKS; b++) { int t = bsum[b]; bsum[b] = acc; acc += t; }
    }
}

__global__ void k_rowptr(const int* __restrict__ deg, const int* __restrict__ bsum,
                         int* __restrict__ row_ptr) {
    __shared__ int sm[256];
    int i = blockIdx.x * 256 + threadIdx.x;
    int v = (i < N_NODES) ? deg[i] : 0;
    sm[threadIdx.x] = v;
    __syncthreads();
    for (int s = 1; s < 256; s <<= 1) {
        int t = (threadIdx.x >= (unsigned)s) ? sm[threadIdx.x - s] : 0;
        __syncthreads();
        sm[threadIdx.x] += t;
        __syncthreads();
    }
    if (i < N_NODES) row_ptr[i] = bsum[blockIdx.x] + sm[threadIdx.x] - v;  // exclusive
}

__global__ void k_scatter(const int* __restrict__ src, const int* __restrict__ dst,
                          const int* __restrict__ row_ptr, int* __restrict__ cursor,
                          int* __restrict__ csr_src) {
    int e = blockIdx.x * 256 + threadIdx.x;
    if (e < N_EDGES) {
        int d = dst[e];
        int pos = atomicAdd(&cursor[d], 1);
        csr_src[row_ptr[d] + pos] = src[e];
    }
}

// h0h = f16(feat @ W_in + b_in)   one wave per node, lane = out col
__global__ __launch_bounds__(256) void k_in_gemm(const float* __restrict__ feat,
                                                 const float* __restrict__ W,
                                                 const float* __restrict__ b,
                                                 u16* __restrict__ h0h) {
    __shared__ float sW[IN_DIM * HID];
    __shared__ float sb[HID];
    int t = threadIdx.x;
    for (int i = t; i < IN_DIM * HID; i += 256) sW[i] = W[i];
    if (t < HID) sb[t] = b[t];
    __syncthreads();
    int wid = (blockIdx.x * 256 + t) >> 6;   // node
    int lane = t & 63;
    const float* f = feat + wid * IN_DIM;
    float acc = sb[lane];
    #pragma unroll
    for (int k = 0; k < IN_DIM; k++) acc += f[k] * sW[k * HID + lane];
    h0h[wid * HID + lane] = f2h(acc);
}

// ---------------- per-layer kernels ----------------

// fs8[N][256] (fp8 e4m3) + fdh[N][256] (f16) = [h|h0] @ Wcat + bcat via MFMA.
// Grid = 782 tile-blocks x 4 col-groups. Block = 4 waves; wave w covers rows
// (tb*4+w)*16..+16, cols g*128..+128. One 32KB W-group in LDS, ONE barrier.
#define ST_STRIDE 152   // u16 per staged C row (304 B: 16B-aligned, bank-spread)
__global__ __launch_bounds__(256) void k_gemm_mfma(const u16* __restrict__ hb,
                                                   const u16* __restrict__ h0b,
                                                   const u16* __restrict__ Wpack,
                                                   const float* __restrict__ bcat,
                                                   u8* __restrict__ fs8,
                                                   u16* __restrict__ fdh) {
    __shared__ u16 sW[16384];          // 32 KB: this col-group's W fragments
    __shared__ u16 sStage[4][2432];    // per-wave C staging (16 rows x 152)
    int tid = threadIdx.x;
    int g  = blockIdx.x & 3;
    int tb = blockIdx.x >> 2;
    int l = tid & 63, w = tid >> 6;
    int lr = l & 15, lg = l >> 4;

    // cooperative load of col-group g's W fragments (32 KB contiguous)
    {
        const f16x8* src = (const f16x8*)(Wpack + g * 16384);
        f16x8* dst = (f16x8*)sW;
        #pragma unroll
        for (int it = 0; it < 8; it++) dst[it * 256 + tid] = src[it * 256 + tid];
    }
    __syncthreads();   // the only barrier

    size_t row0 = (size_t)(tb * 4 + w) * 16;
    if (row0 >= N_NODES) return;   // after the barrier: safe (50000%16==0)

    f32x4 acc[8];
    #pragma unroll
    for (int nt = 0; nt < 8; nt++) acc[nt] = (f32x4){0.f, 0.f, 0.f, 0.f};

    #pragma unroll
    for (int kt = 0; kt < 4; kt++) {
        const u16* A = (kt < 2) ? hb : h0b;
        f16x8 a = *(const f16x8*)(A + (row0 + lr) * HID + (kt & 1) * 32 + lg * 8);
        #pragma unroll
        for (int nt = 0; nt < 8; nt++) {
            f16x8 bfr = *(const f16x8*)(sW + nt * 2048 + kt * 512 + l * 8);
            acc[nt] = __builtin_amdgcn_mfma_f32_16x16x32_f16(a, bfr, acc[nt], 0, 0, 0);
        }
    }

    // C/D layout: acc[nt][j] = C[row0 + lg*4 + j][g*128 + nt*16 + lr]
    u16* myst = sStage[w];   // per-wave slice: no cross-wave sync needed
    #pragma unroll
    for (int nt = 0; nt < 8; nt++) {
        float bv = bcat[g * 128 + nt * 16 + lr];
        #pragma unroll
        for (int j = 0; j < 4; j++)
            myst[(lg * 4 + j) * ST_STRIDE + nt * 16 + lr] = f2h(acc[nt][j] + bv);
    }
    #pragma unroll
    for (int j = 0; j < 4; j++) {
        int rloc = j * 4 + lg;
        f16x8 v = *(const f16x8*)(myst + rloc * ST_STRIDE + lr * 8);
        if (g < 2) {
            int p0 = __builtin_amdgcn_cvt_pk_fp8_f32((float)v[0], (float)v[1], 0, false);
            int p1 = __builtin_amdgcn_cvt_pk_fp8_f32((float)v[2], (float)v[3], 0, false);
            int p2 = __builtin_amdgcn_cvt_pk_fp8_f32((float)v[4], (float)v[5], 0, false);
            int p3 = __builtin_amdgcn_cvt_pk_fp8_f32((float)v[6], (float)v[7], 0, false);
            uint2 o8;
            o8.x = (unsigned)(p0 & 0xffff) | ((unsigned)p1 << 16);
            o8.y = (unsigned)(p2 & 0xffff) | ((unsigned)p3 << 16);
            *(uint2*)(fs8 + (row0 + rloc) * 256 + g * 128 + lr * 8) = o8;
        } else {
            *(f16x8*)(fdh + (row0 + rloc) * 256 + (g - 2) * 128 + lr * 8) = v;
        }
    }
}

// Per dst node: online segment-softmax + weighted aggregation + tanh-headsum.
// One wave per node, 4 edge-groups x 16 lanes, single online state per group,
// defer-max (rescale only when p > m + 4). fp8 unpack via cvt_pk_f32_fp8(word)
// + cvt_pkrtz: ~1 inst/value.
__global__ __launch_bounds__(256) void k_edge(const u8* __restrict__ fs8,
                                              const u16* __restrict__ fdh,
                                              const u16* __restrict__ an_h,
                                              const int* __restrict__ row_ptr,
                                              const int* __restrict__ deg,
                                              const int* __restrict__ csr_src,
                                              u16* __restrict__ h) {
    int wid = (blockIdx.x * 256 + threadIdx.x) >> 6;   // node (grid exact)
    int lane = threadIdx.x & 63;
    int g  = lane >> 4;       // edge group
    int ll = lane & 15;       // element slot
    const size_t ebase = (size_t)ll * 16;

    h2 an[8], fdhv[8];
    {
        const uint4* ap = (const uint4*)(an_h + ebase);
        uint4 a0 = ap[0], a1 = ap[1];
        unsigned aw[8] = {a0.x, a0.y, a0.z, a0.w, a1.x, a1.y, a1.z, a1.w};
        __builtin_memcpy(an, aw, 32);
        const uint4* fp = (const uint4*)(fdh + (size_t)wid * 256 + ebase);
        uint4 b0 = fp[0], b1 = fp[1];
        unsigned fw[8] = {b0.x, b0.y, b0.z, b0.w, b1.x, b1.y, b1.z, b1.w};
        __builtin_memcpy(fdhv, fw, 32);
    }
    const h2 slope2 = {(_Float16)NEG_SLOPE, (_Float16)NEG_SLOPE};

    float m = -3.0e38f, denom = 0.f;
    h2 agg[8];
    #pragma unroll
    for (int q = 0; q < 8; q++) agg[q] = (h2){(_Float16)0.f, (_Float16)0.f};

    int r0 = row_ptr[wid], dg = deg[wid];
    for (int i = g; i < dg; i += 4) {
        int s = csr_src[r0 + i];
        uint4 A = *(const uint4*)(fs8 + (size_t)s * 256 + ebase);   // 16 fp8

        h2 f[8];
        {
            unsigned d[4] = {A.x, A.y, A.z, A.w};
            #pragma unroll
            for (int q = 0; q < 4; q++) {
                f32x2 lo = __builtin_amdgcn_cvt_pk_f32_fp8((int)d[q], false);
                f32x2 hi = __builtin_amdgcn_cvt_pk_f32_fp8((int)d[q], true);
                f[2*q]   = pkrtz_h2(lo[0], lo[1]);
                f[2*q+1] = pkrtz_h2(hi[0], hi[1]);
            }
        }
        float p0 = 0.f, p1 = 0.f;
        #pragma unroll
        for (int q = 0; q < 8; q += 2) {
            h2 e0 = f[q]   + fdhv[q];
            h2 e1 = f[q+1] + fdhv[q+1];
            h2 l0 = __builtin_elementwise_max(e0, e0 * slope2);
            h2 l1 = __builtin_elementwise_max(e1, e1 * slope2);
            p0 = __builtin_amdgcn_fdot2(l0, an[q],   p0, false);
            p1 = __builtin_amdgcn_fdot2(l1, an[q+1], p1, false);
        }
        float p = p0 + p1;
        p += DPP_XOR1(p);
        p += DPP_XOR2(p);            // sum over this head's 16 lanes

        float c;
        if (__builtin_expect(p > m + 4.f, 0)) {    // rare rescale path
            float rs = exp2f(m - p);               // 0 on first edge
            h2 rs2 = bcast_h2(rs);
            #pragma unroll
            for (int q = 0; q < 8; q++) agg[q] = agg[q] * rs2;
            denom *= rs;
            m = p;
            c = 1.f;
        } else {
            c = exp2f(p - m);                      // <= 2^4
        }
        h2 c2 = bcast_h2(c);
        #pragma unroll
        for (int q = 0; q < 8; q++) agg[q] = agg[q] + f[q] * c2;   // 8 pk_fma
        denom += c;
    }

    // cross-group merge: global max, scale once, then butterfly-sum
    {
        float mm = fmaxf(m, __shfl_xor(m, 16));
        mm = fmaxf(mm, __shfl_xor(mm, 32));
        float sc = exp2f(m - mm);
        denom *= sc;
        h2 sc2 = bcast_h2(sc);
        #pragma unroll
        for (int q = 0; q < 8; q++) agg[q] = agg[q] * sc2;
        denom += __shfl_xor(denom, 16);
        denom += __shfl_xor(denom, 32);
        #pragma unroll
        for (int q = 0; q < 8; q++) {
            agg[q] = agg[q] + shfl_h2(agg[q], 16);
            agg[q] = agg[q] + shfl_h2(agg[q], 32);
        }
    }

    float inv = denom > 0.f ? __builtin_amdgcn_rcpf(denom) : 0.f;
    float inv2 = inv * 2.885390082f;   // * 2*log2(e) for tanh via exp2

    // group g handles elements q = 2g, 2g+1 (4 scalars); static selects
    h2 x0 = (g & 2) ? ((g & 1) ? agg[6] : agg[4]) : ((g & 1) ? agg[2] : agg[0]);
    h2 x1 = (g & 2) ? ((g & 1) ? agg[7] : agg[5]) : ((g & 1) ? agg[3] : agg[1]);
    float t[4] = {(float)x0[0], (float)x0[1], (float)x1[0], (float)x1[1]};
    #pragma unroll
    for (int j = 0; j < 4; j++) {
        float E = exp2f(t[j] * inv2);          // tanh(y) = 1 - 2/(e^{2y}+1)
        float r = __builtin_amdgcn_rcpf(E + 1.f);
        float v = fmaf(-2.f, r, 1.f);
        v += __shfl_xor(v, 4);                 // sum over the 4 heads
        v += __shfl_xor(v, 8);
        t[j] = v;
    }
    if (ll < 4) {
        // lane (g, ll) holds dims d = ll*16 + g*4 + {0..3}
        uint2 o;
        o.x = (unsigned)f2h(t[0]) | ((unsigned)f2h(t[1]) << 16);
        o.y = (unsigned)f2h(t[2]) | ((unsigned)f2h(t[3]) << 16);
        *(uint2*)(h + (size_t)wid * 64 + ll * 16 + g * 4) = o;
    }
}

// ---------------- readout ----------------

__global__ __launch_bounds__(256) void k_readout(const u16* __restrict__ h,
                                                 const int* __restrict__ graph_ids,
                                                 const int* __restrict__ is_root,
                                                 float* __restrict__ hg) {
    int wid = (blockIdx.x * 256 + threadIdx.x) >> 6;
    int lane = threadIdx.x & 63;
    if (is_root[wid]) {
        int g = graph_ids[wid];
        atomicAdd(&hg[g * HID + lane], h2f_lo(h[(size_t)wid * HID + lane]));
    }
}

__global__ void k_out_gemm(const float* __restrict__ hg, const float* __restrict__ W,
                           const float* __restrict__ b, float* __restrict__ out) {
    int i = blockIdx.x * 256 + threadIdx.x;
    if (i >= NGRAPH * OUT_DIM) return;
    int g = i >> 5, o = i & 31;
    float acc = b[o];
    #pragma unroll
    for (int k = 0; k < HID; k++) acc += hg[g * HID + k] * W[k * OUT_DIM + o];
    out[i] = acc;
}

// ---------------- host ----------------

extern "C" void kernel_launch(void* const* d_in, const int* in_sizes, int n_in,
                              void* d_out, int out_size, void* d_ws, size_t ws_size,
                              hipStream_t stream) {
    const float* feat      = (const float*)d_in[0];
    const int*   src       = (const int*)d_in[1];
    const int*   dst       = (const int*)d_in[2];
    const int*   graph_ids = (const int*)d_in[3];
    const int*   is_root   = (const int*)d_in[4];
    const float* W_in      = (const float*)d_in[5];
    const float* b_in      = (const float*)d_in[6];
    const float* W_src     = (const float*)d_in[7];
    const float* b_src     = (const float*)d_in[8];
    const float* W_dst     = (const float*)d_in[9];
    const float* b_dst     = (const float*)d_in[10];
    const float* attn      = (const float*)d_in[11];
    const float* W_out     = (const float*)d_in[12];
    const float* b_out     = (const float*)d_in[13];
    float* out = (float*)d_out;

    char* base = (char*)d_ws;
    size_t off = 0;
    auto carve = [&](size_t bytes) -> char* {
        char* p = base + off;
        off = (off + bytes + 255) & ~(size_t)255;
        return p;
    };
    u16*   h0b     = (u16*)carve((size_t)N_NODES * HID * 2);
    u16*   hb      = (u16*)carve((size_t)N_NODES * HID * 2);
    u8*    fs8     = (u8*)carve((size_t)N_NODES * 256);
    u16*   fdh     = (u16*)carve((size_t)N_NODES * 256 * 2);
    u16*   Wpack   = (u16*)carve(128 * 512 * 2);
    float* bcat    = (float*)carve(512 * 4);
    u16*   an_h    = (u16*)carve(256 * 2);
    int*   csr_src = (int*)carve((size_t)N_EDGES * 4);
    int*   row_ptr = (int*)carve((size_t)N_NODES * 4);
    int*   bsum    = (int*)carve(SCAN_BLOCKS * 4);
    char*  zero0   = carve(0);
    int*   deg     = (int*)carve((size_t)N_NODES * 4);
    int*   cursor  = (int*)carve((size_t)N_NODES * 4);
    float* hg      = (float*)carve((size_t)NGRAPH * HID * 4);
    char*  zero1   = base + off;
    if (off > ws_size) return;  // workspace too small -> fail loudly

    (void)hipMemsetAsync(zero0, 0, (size_t)(zero1 - zero0), stream);

    // graph prep
    k_build_wpack<<<256, 256, 0, stream>>>(W_src, b_src, W_dst, b_dst, attn, Wpack, bcat, an_h);
    k_hist<<<(N_EDGES + 255) / 256, 256, 0, stream>>>(dst, deg);
    k_blocksum<<<SCAN_BLOCKS, 256, 0, stream>>>(deg, bsum);
    k_scanbsum<<<1, 64, 0, stream>>>(bsum);
    k_rowptr<<<SCAN_BLOCKS, 256, 0, stream>>>(deg, bsum, row_ptr);
    k_scatter<<<(N_EDGES + 255) / 256, 256, 0, stream>>>(src, dst, row_ptr, cursor, csr_src);

    // input projection
    k_in_gemm<<<N_NODES / 4, 256, 0, stream>>>(feat, W_in, b_in, h0b);

    const int gemm_grid = ((N_NODES / 16 + 3) / 4) * 4;   // 782 tile-blocks x 4 groups
    for (int layer = 0; layer < NUM_LAYERS; layer++) {
        const u16* hcur = (layer == 0) ? h0b : hb;
        k_gemm_mfma<<<gemm_grid, 256, 0, stream>>>(hcur, h0b, Wpack, bcat, fs8, fdh);
        k_edge<<<N_NODES / 4, 256, 0, stream>>>(fs8, fdh, an_h, row_ptr, deg, csr_src, hb);
    }

    k_readout<<<N_NODES / 4, 256, 0, stream>>>(hb, graph_ids, is_root, hg);
    k_out_gemm<<<(NGRAPH * OUT_DIM + 255) / 256, 256, 0, stream>>>(hg, W_out, b_out, out);
}